// Round 3
// baseline (153.967 us; speedup 1.0000x reference)
//
#include <hip/hip_runtime.h>
#include <hip/hip_bf16.h>

// Problem constants
#define BB 4
#define CC 128
#define NN 4096
#define KK 32
// ws layout (floats). NOTE: agg must NOT alias theta (theta is gathered
// concurrently with agg writes inside fused kB).
#define THETA_OFF 0
#define THETA_SZ  (BB*NN*CC)          // 2097152 floats (8 MB)
#define AGG_OFF   (THETA_OFF + THETA_SZ)
#define AGG_SZ    (BB*NN*CC)
#define M_OFF     (AGG_OFF + AGG_SZ)
#define M_SZ      (CC*CC)
#define B2_OFF    (M_OFF + M_SZ)
#define PART_OFF  (B2_OFF + 128)
#define PART_SZ   (512*256)
#define PART2_OFF (PART_OFF + PART_SZ)
#define PART2_SZ  (64*256)
#define STAT_OFF  (PART2_OFF + PART2_SZ)

__device__ __forceinline__ float dot4(float4 a, float4 b) {
    return a.x*b.x + a.y*b.y + a.z*b.z + a.w*b.w;
}

typedef float f4v __attribute__((ext_vector_type(4)));
__device__ __forceinline__ float4 ldnt(const float* p) {
    f4v v = __builtin_nontemporal_load((const f4v*)p);
    float4 r; r.x = v.x; r.y = v.y; r.z = v.z; r.w = v.w; return r;
}

// ---------------- Kernel WT: theta GEMM (blocks 0..511) + weight combine (512..576) ----
// theta_all = xr @ Wt^T + bt ; M = Ww @ Wg ; b2 = Ww @ bg + bw
__global__ __launch_bounds__(256) void kWT(const float* __restrict__ x,
                                           const float* __restrict__ Wt,
                                           const float* __restrict__ bt,
                                           const float* __restrict__ Ww,
                                           const float* __restrict__ Wg,
                                           const float* __restrict__ bg,
                                           const float* __restrict__ bw,
                                           float* __restrict__ theta,
                                           float* __restrict__ M,
                                           float* __restrict__ b2) {
    __shared__ float xr[32][132];
    __shared__ float wt[128][36];
    int t = threadIdx.x;
    if (blockIdx.x >= 512) {
        int bid2 = blockIdx.x - 512;
        if (bid2 < 64) {
            int e = bid2 * 2 + (t >> 7);
            int c = t & 127;
            float acc = 0.f;
#pragma unroll 8
            for (int d = 0; d < 128; ++d)
                acc += Ww[e*128 + d] * Wg[d*128 + c];
            M[e*128 + c] = acc;
        } else if (t < 128) {
            float acc = bw[t];
            for (int d = 0; d < 128; ++d)
                acc += Ww[t*128 + d] * bg[d];
            b2[t] = acc;
        }
        return;
    }
    long base = (long)blockIdx.x * (32 * 128);
#pragma unroll
    for (int r = 0; r < 4; ++r) {
        int f = (t + 256*r) * 4;
        int dn = f >> 7, c = f & 127;
        *(float4*)&xr[dn][c] = *(const float4*)(x + base + f);
    }
    float acc[4][4] = {};
    int e0 = t & 31, dn0 = (t >> 5) * 4;
    for (int cb = 0; cb < 4; ++cb) {
        __syncthreads();
#pragma unroll
        for (int r = 0; r < 4; ++r) {
            int f = (t + 256*r) * 4;
            int d = f >> 5, cc = f & 31;
            *(float4*)&wt[d][cc] = *(const float4*)(Wt + d*128 + cb*32 + cc);
        }
        __syncthreads();
#pragma unroll
        for (int q = 0; q < 8; ++q) {
            float4 a4[4], m4[4];
#pragma unroll
            for (int j = 0; j < 4; ++j) a4[j] = *(const float4*)&xr[dn0+j][cb*32 + q*4];
#pragma unroll
            for (int i = 0; i < 4; ++i) m4[i] = *(const float4*)&wt[e0 + 32*i][q*4];
#pragma unroll
            for (int i = 0; i < 4; ++i)
#pragma unroll
                for (int j = 0; j < 4; ++j)
                    acc[i][j] += dot4(a4[j], m4[i]);
        }
    }
    __syncthreads();
#pragma unroll
    for (int i = 0; i < 4; ++i) {
        float b = bt[e0 + 32*i];
#pragma unroll
        for (int j = 0; j < 4; ++j)
            xr[dn0 + j][e0 + 32*i] = acc[i][j] + b;
    }
    __syncthreads();
#pragma unroll
    for (int r = 0; r < 4; ++r) {
        int f = (t + 256*r) * 4;
        int dn = f >> 7, c = f & 127;
        *(float4*)(theta + base + f) = *(const float4*)&xr[dn][c];
    }
}

// ---------------- Kernel B (fused coef + aggregation) ----------------
// Block = (tile of 32 n) x (32-channel chunk). Grid = 512*4 = 2048.
// Phase A: stage theta tile; gather theta[idx]; logits; softmax -> coef (LDS).
// Phase B: agg[n][c] = sum_k coef[n][k] * feature[b][c][n][k]  (nontemporal stream).
union UB {
    struct { float tc[32][132]; float logits[32][33]; } a;
    float ag[32][36];
};

__global__ __launch_bounds__(256, 5) void kB(const int* __restrict__ gi,
                                             const float* __restrict__ theta,
                                             const float* __restrict__ feat,
                                             float* __restrict__ aggG) {
    __shared__ UB u;
    __shared__ float coef[32][36];
    int t = threadIdx.x;
    int cc4 = blockIdx.x & 3;
    int tile = blockIdx.x >> 2;          // b*128 + nt
    int b = tile >> 7;
    int n0 = (tile & 127) * 32;
    long trow0 = (long)tile * 32;        // = b*N + n0
    int l8 = t & 7;

    // ---- stage 32 theta rows (16 KB contiguous) ----
#pragma unroll
    for (int r = 0; r < 4; ++r) {
        int f = (t + 256*r) * 4;
        int dn = f >> 7, c = f & 127;
        *(float4*)&u.a.tc[dn][c] = *(const float4*)(theta + trow0*128 + f);
    }
    __syncthreads();

    // ---- logits via gather ----
    {
        int k = t >> 3;
        const float* tbat = theta + (long)b * NN * CC;
        for (int dn = 0; dn < 32; ++dn) {
            int idx = gi[(trow0 + dn) * KK + k];
            const float* row = tbat + (long)idx * CC;
            float p = 0.f;
#pragma unroll
            for (int j = 0; j < 4; ++j) {
                int c = j*32 + l8*4;
                float4 g = *(const float4*)(row + c);
                float4 tcv = *(const float4*)&u.a.tc[dn][c];
                p += dot4(g, tcv);
            }
            p += __shfl_xor(p, 1);
            p += __shfl_xor(p, 2);
            p += __shfl_xor(p, 4);
            if (l8 == 0) u.a.logits[dn][k] = p;
        }
    }
    __syncthreads();

    // ---- softmax over k (8 lanes per row, 32 rows => all 256 threads) ----
    {
        int row = t >> 3;
        float l[4];
#pragma unroll
        for (int j = 0; j < 4; ++j) l[j] = u.a.logits[row][l8 + 8*j];
        float m = fmaxf(fmaxf(l[0], l[1]), fmaxf(l[2], l[3]));
        m = fmaxf(m, __shfl_xor(m, 1));
        m = fmaxf(m, __shfl_xor(m, 2));
        m = fmaxf(m, __shfl_xor(m, 4));
        float e[4]; float s = 0.f;
#pragma unroll
        for (int j = 0; j < 4; ++j) { e[j] = __expf(l[j] - m); s += e[j]; }
        s += __shfl_xor(s, 1);
        s += __shfl_xor(s, 2);
        s += __shfl_xor(s, 4);
        float inv = 1.0f / s;
#pragma unroll
        for (int j = 0; j < 4; ++j) coef[row][l8 + 8*j] = e[j] * inv;
    }
    __syncthreads();   // u.a dead from here; u.ag live

    // ---- phase B: stream feature chunk ----
    {
        int dn = t >> 3, k4i = l8 * 4;
        float4 cf = *(const float4*)&coef[dn][k4i];
        const size_t S = (size_t)NN * KK;
        const float* fb = feat + ((size_t)b * CC + cc4 * 32) * S + (size_t)(n0 + dn) * KK + k4i;
        for (int c0 = 0; c0 < 32; c0 += 8) {
            float4 f[8];
#pragma unroll
            for (int i = 0; i < 8; ++i)
                f[i] = ldnt(fb + (size_t)(c0 + i) * S);
            float v[8];
#pragma unroll
            for (int i = 0; i < 8; ++i) {
                v[i] = dot4(f[i], cf);
                v[i] += __shfl_xor(v[i], 1);
                v[i] += __shfl_xor(v[i], 2);
                v[i] += __shfl_xor(v[i], 4);
            }
            if (l8 == 0) {
#pragma unroll
                for (int i = 0; i < 8; ++i) u.ag[dn][c0 + i] = v[i];
            }
        }
    }
    __syncthreads();
    int row = t >> 3, col4 = l8 * 4;
    *(float4*)(aggG + ((size_t)b * NN + n0 + row) * CC + cc4 * 32 + col4) =
        *(const float4*)&u.ag[row][col4];
}

// ---------------- Kernel C: y = agg @ M^T + b2; BN partials ----------------
__global__ __launch_bounds__(256) void kC(const float* __restrict__ aggG,
                                          const float* __restrict__ Mmat,
                                          const float* __restrict__ b2v,
                                          float* __restrict__ y,
                                          float* __restrict__ partial) {
    __shared__ float agg[32][132];
    __shared__ float mc[128][36];
    __shared__ float pw[4][128];
    __shared__ float qw[4][128];
    int t = threadIdx.x;
    int b = blockIdx.x >> 7;
    int n0 = (blockIdx.x & 127) * 32;
    long base = (long)blockIdx.x * (32 * 128);
#pragma unroll
    for (int r = 0; r < 4; ++r) {
        int f = (t + 256*r) * 4;
        int dn = f >> 7, c = f & 127;
        *(float4*)&agg[dn][c] = *(const float4*)(aggG + base + f);
    }
    float acc[4][4] = {};
    int e0 = t & 31, dn0 = (t >> 5) * 4;
    for (int cb = 0; cb < 4; ++cb) {
        __syncthreads();
#pragma unroll
        for (int r = 0; r < 4; ++r) {
            int f = (t + 256*r) * 4;
            int e = f >> 5, cc = f & 31;
            *(float4*)&mc[e][cc] = *(const float4*)(Mmat + e*128 + cb*32 + cc);
        }
        __syncthreads();
#pragma unroll
        for (int q = 0; q < 8; ++q) {
            float4 a4[4], m4[4];
#pragma unroll
            for (int j = 0; j < 4; ++j) a4[j] = *(const float4*)&agg[dn0+j][cb*32 + q*4];
#pragma unroll
            for (int i = 0; i < 4; ++i) m4[i] = *(const float4*)&mc[e0 + 32*i][q*4];
#pragma unroll
            for (int i = 0; i < 4; ++i)
#pragma unroll
                for (int j = 0; j < 4; ++j)
                    acc[i][j] += dot4(a4[j], m4[i]);
        }
        __syncthreads();
    }
    int w = t >> 6;
#pragma unroll
    for (int i = 0; i < 4; ++i) {
        int e = e0 + 32*i;
        float bb = b2v[e];
        float4 yv;
        yv.x = acc[i][0] + bb;
        yv.y = acc[i][1] + bb;
        yv.z = acc[i][2] + bb;
        yv.w = acc[i][3] + bb;
        *(float4*)(y + ((long)(b*CC + e)) * NN + n0 + dn0) = yv;
        float s = yv.x + yv.y + yv.z + yv.w;
        float qq = yv.x*yv.x + yv.y*yv.y + yv.z*yv.z + yv.w*yv.w;
        s  += __shfl_xor(s, 32);
        qq += __shfl_xor(qq, 32);
        if (!(t & 32)) { pw[w][e] = s; qw[w][e] = qq; }
    }
    __syncthreads();
    if (t < 128) {
        partial[(long)blockIdx.x * 256 + t]       = pw[0][t] + pw[1][t] + pw[2][t] + pw[3][t];
        partial[(long)blockIdx.x * 256 + 128 + t] = qw[0][t] + qw[1][t] + qw[2][t] + qw[3][t];
    }
}

// ---------------- Kernel R1: 512 partial rows -> 64 ----------------
__global__ __launch_bounds__(256) void kR1(const float* __restrict__ partial,
                                           float* __restrict__ partial2) {
    int t = threadIdx.x;
    long b0 = (long)blockIdx.x * 8;
    float acc = 0.f;
#pragma unroll
    for (int j = 0; j < 8; ++j)
        acc += partial[(b0 + j) * 256 + t];
    partial2[(long)blockIdx.x * 256 + t] = acc;
}

// ---------------- Kernel R2: 64 rows -> stats ----------------
__global__ __launch_bounds__(256) void kR2(const float* __restrict__ partial2,
                                           const float* __restrict__ gamma,
                                           const float* __restrict__ beta,
                                           float* __restrict__ stats) {
    __shared__ float buf[256];
    int t = threadIdx.x;
    float acc = 0.f;
#pragma unroll
    for (int j = 0; j < 64; ++j)
        acc += partial2[j * 256 + t];
    buf[t] = acc;
    __syncthreads();
    if (t < 128) {
        float S = buf[t], Q = buf[t + 128];
        const float invN = 1.0f / (BB * NN);
        float mean = S * invN;
        float var  = Q * invN - mean * mean;
        float sc = rsqrtf(var + 1e-5f) * gamma[t];
        stats[t]       = sc;
        stats[128 + t] = beta[t] - mean * sc;
    }
}

// ---------------- Kernel Z: in-place normalize ----------------
__global__ void kZ(float* __restrict__ y, const float* __restrict__ stats) {
    int idx = blockIdx.x * 256 + threadIdx.x;   // float4 index
#pragma unroll
    for (int r = 0; r < 2; ++r) {
        int i = idx + r * 262144;
        int e = (i >> 10) & 127;
        float sc = stats[e], sh = stats[128 + e];
        float4 v = ((float4*)y)[i];
        v.x = v.x * sc + sh;
        v.y = v.y * sc + sh;
        v.z = v.z * sc + sh;
        v.w = v.w * sc + sh;
        ((float4*)y)[i] = v;
    }
}

extern "C" void kernel_launch(void* const* d_in, const int* in_sizes, int n_in,
                              void* d_out, int out_size, void* d_ws, size_t ws_size,
                              hipStream_t stream) {
    const int*   gi    = (const int*)d_in[0];
    const float* x     = (const float*)d_in[1];
    const float* feat  = (const float*)d_in[2];
    const float* Wt    = (const float*)d_in[3];
    const float* bt    = (const float*)d_in[4];
    const float* Wg    = (const float*)d_in[5];
    const float* bg    = (const float*)d_in[6];
    const float* Ww    = (const float*)d_in[7];
    const float* bw    = (const float*)d_in[8];
    const float* gamma = (const float*)d_in[9];
    const float* beta  = (const float*)d_in[10];

    float* y  = (float*)d_out;
    float* ws = (float*)d_ws;
    float* theta    = ws + THETA_OFF;
    float* aggG     = ws + AGG_OFF;
    float* Mmat     = ws + M_OFF;
    float* b2       = ws + B2_OFF;
    float* partial  = ws + PART_OFF;
    float* partial2 = ws + PART2_OFF;
    float* stats    = ws + STAT_OFF;

    kWT<<<577, 256, 0, stream>>>(x, Wt, bt, Ww, Wg, bg, bw, theta, Mmat, b2);
    kB<<<2048, 256, 0, stream>>>(gi, theta, feat, aggG);
    kC<<<512, 256, 0, stream>>>(aggG, Mmat, b2, y, partial);
    kR1<<<64, 256, 0, stream>>>(partial, partial2);
    kR2<<<1, 256, 0, stream>>>(partial2, gamma, beta, stats);
    kZ<<<1024, 256, 0, stream>>>(y, stats);
}

// Round 4
// 114.006 us; speedup vs baseline: 1.3505x; 1.3505x over previous
//
#include <hip/hip_runtime.h>
#include <hip/hip_bf16.h>

// Problem constants
#define BB 4
#define CC 128
#define NN 4096
#define KK 32
// ws layout (floats)
#define THETA_OFF 0
#define THETA_SZ  (BB*NN*CC)          // 2097152 floats (8 MB)
#define AGG_OFF   (THETA_OFF + THETA_SZ)
#define AGG_SZ    (BB*NN*CC)
#define M_OFF     (AGG_OFF + AGG_SZ)
#define M_SZ      (CC*CC)
#define B2_OFF    (M_OFF + M_SZ)
#define COEF_OFF  (B2_OFF + 128)
#define COEF_SZ   (BB*NN*KK)
#define PART_OFF  (COEF_OFF + COEF_SZ)
#define PART_SZ   (512*256)
#define PART2_OFF (PART_OFF + PART_SZ)
#define PART2_SZ  (64*256)
#define STAT_OFF  (PART2_OFF + PART2_SZ)

__device__ __forceinline__ float dot4(float4 a, float4 b) {
    return a.x*b.x + a.y*b.y + a.z*b.z + a.w*b.w;
}

// async global->LDS DMA, 16B per lane. LDS dest must be wave-uniform base
// (HW writes base + lane*16); global src is per-lane.
__device__ __forceinline__ void async_copy16(const float* g, float* l) {
    __builtin_amdgcn_global_load_lds(
        (const __attribute__((address_space(1))) void*)g,
        (__attribute__((address_space(3))) void*)l, 16, 0, 0);
}

// ---------------- Kernel WT: theta GEMM (blocks 0..511) + weight combine (512..576) ----
__global__ __launch_bounds__(256) void kWT(const float* __restrict__ x,
                                           const float* __restrict__ Wt,
                                           const float* __restrict__ bt,
                                           const float* __restrict__ Ww,
                                           const float* __restrict__ Wg,
                                           const float* __restrict__ bg,
                                           const float* __restrict__ bw,
                                           float* __restrict__ theta,
                                           float* __restrict__ M,
                                           float* __restrict__ b2) {
    __shared__ float xr[32][132];
    __shared__ float wt[128][36];
    int t = threadIdx.x;
    if (blockIdx.x >= 512) {
        int bid2 = blockIdx.x - 512;
        if (bid2 < 64) {
            int e = bid2 * 2 + (t >> 7);
            int c = t & 127;
            float acc = 0.f;
#pragma unroll 8
            for (int d = 0; d < 128; ++d)
                acc += Ww[e*128 + d] * Wg[d*128 + c];
            M[e*128 + c] = acc;
        } else if (t < 128) {
            float acc = bw[t];
            for (int d = 0; d < 128; ++d)
                acc += Ww[t*128 + d] * bg[d];
            b2[t] = acc;
        }
        return;
    }
    long base = (long)blockIdx.x * (32 * 128);
#pragma unroll
    for (int r = 0; r < 4; ++r) {
        int f = (t + 256*r) * 4;
        int dn = f >> 7, c = f & 127;
        *(float4*)&xr[dn][c] = *(const float4*)(x + base + f);
    }
    float acc[4][4] = {};
    int e0 = t & 31, dn0 = (t >> 5) * 4;
    for (int cb = 0; cb < 4; ++cb) {
        __syncthreads();
#pragma unroll
        for (int r = 0; r < 4; ++r) {
            int f = (t + 256*r) * 4;
            int d = f >> 5, cc = f & 31;
            *(float4*)&wt[d][cc] = *(const float4*)(Wt + d*128 + cb*32 + cc);
        }
        __syncthreads();
#pragma unroll
        for (int q = 0; q < 8; ++q) {
            float4 a4[4], m4[4];
#pragma unroll
            for (int j = 0; j < 4; ++j) a4[j] = *(const float4*)&xr[dn0+j][cb*32 + q*4];
#pragma unroll
            for (int i = 0; i < 4; ++i) m4[i] = *(const float4*)&wt[e0 + 32*i][q*4];
#pragma unroll
            for (int i = 0; i < 4; ++i)
#pragma unroll
                for (int j = 0; j < 4; ++j)
                    acc[i][j] += dot4(a4[j], m4[i]);
        }
    }
    __syncthreads();
#pragma unroll
    for (int i = 0; i < 4; ++i) {
        float b = bt[e0 + 32*i];
#pragma unroll
        for (int j = 0; j < 4; ++j)
            xr[dn0 + j][e0 + 32*i] = acc[i][j] + b;
    }
    __syncthreads();
#pragma unroll
    for (int r = 0; r < 4; ++r) {
        int f = (t + 256*r) * 4;
        int dn = f >> 7, c = f & 127;
        *(float4*)(theta + base + f) = *(const float4*)&xr[dn][c];
    }
}

// ---------------- Kernel A: coef = softmax_k(theta[n] . theta[idx[n,k]]) ----------------
__global__ __launch_bounds__(256) void kA(const int* __restrict__ gi,
                                          const float* __restrict__ theta,
                                          float* __restrict__ coefG) {
    __shared__ float tc[16][132];
    __shared__ float logits[16][33];
    int t = threadIdx.x;
    long trow0 = (long)blockIdx.x * 16;
    int b = blockIdx.x >> 8;
    int k = t >> 3, l8 = t & 7;
#pragma unroll
    for (int r = 0; r < 2; ++r) {
        int f = (t + 256*r) * 4;
        int dn = f >> 7, c = f & 127;
        *(float4*)&tc[dn][c] = *(const float4*)(theta + trow0*128 + f);
    }
    int idxs[16];
#pragma unroll
    for (int dn = 0; dn < 16; ++dn)
        idxs[dn] = gi[(trow0 + dn) * KK + k];
    __syncthreads();
    const float* tbat = theta + (long)b * NN * CC;
#pragma unroll 2
    for (int dn = 0; dn < 16; ++dn) {
        const float* row = tbat + (long)idxs[dn] * CC;
        float p = 0.f;
#pragma unroll
        for (int j = 0; j < 4; ++j) {
            int c = j*32 + l8*4;
            float4 g = *(const float4*)(row + c);
            float4 tcv = *(const float4*)&tc[dn][c];
            p += dot4(g, tcv);
        }
        p += __shfl_xor(p, 1);
        p += __shfl_xor(p, 2);
        p += __shfl_xor(p, 4);
        if (l8 == 0) logits[dn][k] = p;
    }
    __syncthreads();
    if (t < 128) {
        int row = t >> 3;
        float l[4];
#pragma unroll
        for (int j = 0; j < 4; ++j) l[j] = logits[row][l8 + 8*j];
        float m = fmaxf(fmaxf(l[0], l[1]), fmaxf(l[2], l[3]));
        m = fmaxf(m, __shfl_xor(m, 1));
        m = fmaxf(m, __shfl_xor(m, 2));
        m = fmaxf(m, __shfl_xor(m, 4));
        float e[4]; float s = 0.f;
#pragma unroll
        for (int j = 0; j < 4; ++j) { e[j] = __expf(l[j] - m); s += e[j]; }
        s += __shfl_xor(s, 1);
        s += __shfl_xor(s, 2);
        s += __shfl_xor(s, 4);
        float inv = 1.0f / s;
#pragma unroll
        for (int j = 0; j < 4; ++j)
            coefG[(trow0 + row) * KK + l8 + 8*j] = e[j] * inv;
    }
}

// ---------------- Kernel B: agg[n][c] = sum_k coef[n][k]*feature[b][c][n][k] ----------------
// Block = 32n x 32c chunk; 8 sub-chunks of 4 channels, DMA double-buffered.
// Source k-segments pre-rotated by row ((s-r)&7) so LDS stays linear for DMA;
// compute reads with the matching rotation ((l8+dn)&7).
__global__ __launch_bounds__(256) void kB(const float* __restrict__ coefG,
                                          const float* __restrict__ feat,
                                          float* __restrict__ aggG) {
    __shared__ float stage[2][4][32][32];   // [buf][c_local][n][k] 2x16KB
    __shared__ float aggL[32][36];
    int t = threadIdx.x;
    int cc4 = blockIdx.x & 3;
    int tile = blockIdx.x >> 2;          // b*128 + nt
    int b = tile >> 7;
    int n0 = (tile & 127) * 32;
    int dn = t >> 3, l8 = t & 7;
    int w = t >> 6, lane = t & 63;
    int r = lane >> 3, s = lane & 7;
    int rot = ((s - r) & 7) * 4;

    float4 cf = *(const float4*)(coefG + ((size_t)tile * 32 + dn) * KK + l8 * 4);

    const size_t S = (size_t)NN * KK;
    const float* fbase = feat + ((size_t)b * CC + cc4 * 32) * S + (size_t)n0 * KK;

    // stage chunk 0 (wave w stages its channel c_local = w)
    {
        const float* fc = fbase + (size_t)w * S;
#pragma unroll
        for (int i = 0; i < 4; ++i)
            async_copy16(fc + (i*8 + r)*KK + rot, &stage[0][w][i*8][0]);
    }
    __syncthreads();
    int buf = 0;
    for (int ch = 0; ch < 8; ++ch) {
        if (ch < 7) {
            const float* fc = fbase + (size_t)((ch+1)*4 + w) * S;
#pragma unroll
            for (int i = 0; i < 4; ++i)
                async_copy16(fc + (i*8 + r)*KK + rot, &stage[buf^1][w][i*8][0]);
        }
#pragma unroll
        for (int cl = 0; cl < 4; ++cl) {
            float4 f = *(const float4*)&stage[buf][cl][dn][((l8 + dn) & 7) * 4];
            float v = dot4(f, cf);
            v += __shfl_xor(v, 1);
            v += __shfl_xor(v, 2);
            v += __shfl_xor(v, 4);
            if (l8 == 0) aggL[dn][ch*4 + cl] = v;
        }
        __syncthreads();   // drains vmcnt -> next buf staged; LDS reads done
        buf ^= 1;
    }
    int row = t >> 3, col4 = l8 * 4;
    *(float4*)(aggG + ((size_t)b * NN + n0 + row) * CC + cc4 * 32 + col4) =
        *(const float4*)&aggL[row][col4];
}

// ---------------- Kernel C: y = agg @ M^T + b2; BN partials ----------------
__global__ __launch_bounds__(256) void kC(const float* __restrict__ aggG,
                                          const float* __restrict__ Mmat,
                                          const float* __restrict__ b2v,
                                          float* __restrict__ y,
                                          float* __restrict__ partial) {
    __shared__ float agg[32][132];
    __shared__ float mc[128][36];
    __shared__ float pw[4][128];
    __shared__ float qw[4][128];
    int t = threadIdx.x;
    int b = blockIdx.x >> 7;
    int n0 = (blockIdx.x & 127) * 32;
    long base = (long)blockIdx.x * (32 * 128);
#pragma unroll
    for (int r = 0; r < 4; ++r) {
        int f = (t + 256*r) * 4;
        int dn = f >> 7, c = f & 127;
        *(float4*)&agg[dn][c] = *(const float4*)(aggG + base + f);
    }
    float acc[4][4] = {};
    int e0 = t & 31, dn0 = (t >> 5) * 4;
    for (int cb = 0; cb < 4; ++cb) {
        __syncthreads();
#pragma unroll
        for (int r = 0; r < 4; ++r) {
            int f = (t + 256*r) * 4;
            int e = f >> 5, cc = f & 31;
            *(float4*)&mc[e][cc] = *(const float4*)(Mmat + e*128 + cb*32 + cc);
        }
        __syncthreads();
#pragma unroll
        for (int q = 0; q < 8; ++q) {
            float4 a4[4], m4[4];
#pragma unroll
            for (int j = 0; j < 4; ++j) a4[j] = *(const float4*)&agg[dn0+j][cb*32 + q*4];
#pragma unroll
            for (int i = 0; i < 4; ++i) m4[i] = *(const float4*)&mc[e0 + 32*i][q*4];
#pragma unroll
            for (int i = 0; i < 4; ++i)
#pragma unroll
                for (int j = 0; j < 4; ++j)
                    acc[i][j] += dot4(a4[j], m4[i]);
        }
        __syncthreads();
    }
    int w = t >> 6;
#pragma unroll
    for (int i = 0; i < 4; ++i) {
        int e = e0 + 32*i;
        float bb = b2v[e];
        float4 yv;
        yv.x = acc[i][0] + bb;
        yv.y = acc[i][1] + bb;
        yv.z = acc[i][2] + bb;
        yv.w = acc[i][3] + bb;
        *(float4*)(y + ((long)(b*CC + e)) * NN + n0 + dn0) = yv;
        float s = yv.x + yv.y + yv.z + yv.w;
        float qq = yv.x*yv.x + yv.y*yv.y + yv.z*yv.z + yv.w*yv.w;
        s  += __shfl_xor(s, 32);
        qq += __shfl_xor(qq, 32);
        if (!(t & 32)) { pw[w][e] = s; qw[w][e] = qq; }
    }
    __syncthreads();
    if (t < 128) {
        partial[(long)blockIdx.x * 256 + t]       = pw[0][t] + pw[1][t] + pw[2][t] + pw[3][t];
        partial[(long)blockIdx.x * 256 + 128 + t] = qw[0][t] + qw[1][t] + qw[2][t] + qw[3][t];
    }
}

// ---------------- Kernel R1: 512 partial rows -> 64 ----------------
__global__ __launch_bounds__(256) void kR1(const float* __restrict__ partial,
                                           float* __restrict__ partial2) {
    int t = threadIdx.x;
    long b0 = (long)blockIdx.x * 8;
    float acc = 0.f;
#pragma unroll
    for (int j = 0; j < 8; ++j)
        acc += partial[(b0 + j) * 256 + t];
    partial2[(long)blockIdx.x * 256 + t] = acc;
}

// ---------------- Kernel R2: 64 rows -> stats ----------------
__global__ __launch_bounds__(256) void kR2(const float* __restrict__ partial2,
                                           const float* __restrict__ gamma,
                                           const float* __restrict__ beta,
                                           float* __restrict__ stats) {
    __shared__ float buf[256];
    int t = threadIdx.x;
    float acc = 0.f;
#pragma unroll
    for (int j = 0; j < 64; ++j)
        acc += partial2[j * 256 + t];
    buf[t] = acc;
    __syncthreads();
    if (t < 128) {
        float S = buf[t], Q = buf[t + 128];
        const float invN = 1.0f / (BB * NN);
        float mean = S * invN;
        float var  = Q * invN - mean * mean;
        float sc = rsqrtf(var + 1e-5f) * gamma[t];
        stats[t]       = sc;
        stats[128 + t] = beta[t] - mean * sc;
    }
}

// ---------------- Kernel Z: in-place normalize ----------------
__global__ void kZ(float* __restrict__ y, const float* __restrict__ stats) {
    int idx = blockIdx.x * 256 + threadIdx.x;   // float4 index
#pragma unroll
    for (int r = 0; r < 2; ++r) {
        int i = idx + r * 262144;
        int e = (i >> 10) & 127;
        float sc = stats[e], sh = stats[128 + e];
        float4 v = ((float4*)y)[i];
        v.x = v.x * sc + sh;
        v.y = v.y * sc + sh;
        v.z = v.z * sc + sh;
        v.w = v.w * sc + sh;
        ((float4*)y)[i] = v;
    }
}

extern "C" void kernel_launch(void* const* d_in, const int* in_sizes, int n_in,
                              void* d_out, int out_size, void* d_ws, size_t ws_size,
                              hipStream_t stream) {
    const int*   gi    = (const int*)d_in[0];
    const float* x     = (const float*)d_in[1];
    const float* feat  = (const float*)d_in[2];
    const float* Wt    = (const float*)d_in[3];
    const float* bt    = (const float*)d_in[4];
    const float* Wg    = (const float*)d_in[5];
    const float* bg    = (const float*)d_in[6];
    const float* Ww    = (const float*)d_in[7];
    const float* bw    = (const float*)d_in[8];
    const float* gamma = (const float*)d_in[9];
    const float* beta  = (const float*)d_in[10];

    float* y  = (float*)d_out;
    float* ws = (float*)d_ws;
    float* theta    = ws + THETA_OFF;
    float* aggG     = ws + AGG_OFF;
    float* Mmat     = ws + M_OFF;
    float* b2       = ws + B2_OFF;
    float* coefG    = ws + COEF_OFF;
    float* partial  = ws + PART_OFF;
    float* partial2 = ws + PART2_OFF;
    float* stats    = ws + STAT_OFF;

    kWT<<<577, 256, 0, stream>>>(x, Wt, bt, Ww, Wg, bg, bw, theta, Mmat, b2);
    kA<<<1024, 256, 0, stream>>>(gi, theta, coefG);
    kB<<<2048, 256, 0, stream>>>(coefG, feat, aggG);
    kC<<<512, 256, 0, stream>>>(aggG, Mmat, b2, y, partial);
    kR1<<<64, 256, 0, stream>>>(partial, partial2);
    kR2<<<1, 256, 0, stream>>>(partial2, gamma, beta, stats);
    kZ<<<1024, 256, 0, stream>>>(y, stats);
}

// Round 6
// 107.233 us; speedup vs baseline: 1.4358x; 1.0632x over previous
//
#include <hip/hip_runtime.h>
#include <hip/hip_bf16.h>

// Problem constants
#define BB 4
#define CC 128
#define NN 4096
#define KK 32
// ws layout (floats)
#define THETA_OFF 0
#define THETA_SZ  (BB*NN*CC)          // 2097152 floats (8 MB)
#define AGG_OFF   (THETA_OFF + THETA_SZ)
#define AGG_SZ    (BB*NN*CC)
#define M_OFF     (AGG_OFF + AGG_SZ)
#define M_SZ      (CC*CC)
#define B2_OFF    (M_OFF + M_SZ)
#define COEF_OFF  (B2_OFF + 128)
#define COEF_SZ   (BB*NN*KK)
#define PART_OFF  (COEF_OFF + COEF_SZ)
#define PART_SZ   (512*256)
#define PART2_OFF (PART_OFF + PART_SZ)
#define PART2_SZ  (64*256)
#define STAT_OFF  (PART2_OFF + PART2_SZ)

__device__ __forceinline__ float dot4(float4 a, float4 b) {
    return a.x*b.x + a.y*b.y + a.z*b.z + a.w*b.w;
}

// async global->LDS DMA, 16B per lane. LDS dest is wave-uniform base
// (HW writes base + lane*16); global src is per-lane.
__device__ __forceinline__ void async_copy16(const float* g, float* l) {
    __builtin_amdgcn_global_load_lds(
        (const __attribute__((address_space(1))) void*)g,
        (__attribute__((address_space(3))) void*)l, 16, 0, 0);
}

// raw barrier without the vmcnt(0) drain that __syncthreads() emits
#define SYNCB() do { asm volatile("" ::: "memory"); \
                     __builtin_amdgcn_s_barrier(); \
                     asm volatile("" ::: "memory"); } while (0)

// ---------------- Kernel WT: theta GEMM (blocks 0..511) + weight combine (512..576) ----
__global__ __launch_bounds__(256) void kWT(const float* __restrict__ x,
                                           const float* __restrict__ Wt,
                                           const float* __restrict__ bt,
                                           const float* __restrict__ Ww,
                                           const float* __restrict__ Wg,
                                           const float* __restrict__ bg,
                                           const float* __restrict__ bw,
                                           float* __restrict__ theta,
                                           float* __restrict__ M,
                                           float* __restrict__ b2) {
    __shared__ float xr[32][132];
    __shared__ float wt[128][36];
    int t = threadIdx.x;
    if (blockIdx.x >= 512) {
        int bid2 = blockIdx.x - 512;
        if (bid2 < 64) {
            int e = bid2 * 2 + (t >> 7);
            int c = t & 127;
            float acc = 0.f;
#pragma unroll 8
            for (int d = 0; d < 128; ++d)
                acc += Ww[e*128 + d] * Wg[d*128 + c];
            M[e*128 + c] = acc;
        } else if (t < 128) {
            float acc = bw[t];
            for (int d = 0; d < 128; ++d)
                acc += Ww[t*128 + d] * bg[d];
            b2[t] = acc;
        }
        return;
    }
    long base = (long)blockIdx.x * (32 * 128);
#pragma unroll
    for (int r = 0; r < 4; ++r) {
        int f = (t + 256*r) * 4;
        int dn = f >> 7, c = f & 127;
        *(float4*)&xr[dn][c] = *(const float4*)(x + base + f);
    }
    float acc[4][4] = {};
    int e0 = t & 31, dn0 = (t >> 5) * 4;
    for (int cb = 0; cb < 4; ++cb) {
        __syncthreads();
#pragma unroll
        for (int r = 0; r < 4; ++r) {
            int f = (t + 256*r) * 4;
            int d = f >> 5, cc = f & 31;
            *(float4*)&wt[d][cc] = *(const float4*)(Wt + d*128 + cb*32 + cc);
        }
        __syncthreads();
#pragma unroll
        for (int q = 0; q < 8; ++q) {
            float4 a4[4], m4[4];
#pragma unroll
            for (int j = 0; j < 4; ++j) a4[j] = *(const float4*)&xr[dn0+j][cb*32 + q*4];
#pragma unroll
            for (int i = 0; i < 4; ++i) m4[i] = *(const float4*)&wt[e0 + 32*i][q*4];
#pragma unroll
            for (int i = 0; i < 4; ++i)
#pragma unroll
                for (int j = 0; j < 4; ++j)
                    acc[i][j] += dot4(a4[j], m4[i]);
        }
    }
    __syncthreads();
#pragma unroll
    for (int i = 0; i < 4; ++i) {
        float b = bt[e0 + 32*i];
#pragma unroll
        for (int j = 0; j < 4; ++j)
            xr[dn0 + j][e0 + 32*i] = acc[i][j] + b;
    }
    __syncthreads();
#pragma unroll
    for (int r = 0; r < 4; ++r) {
        int f = (t + 256*r) * 4;
        int dn = f >> 7, c = f & 127;
        *(float4*)(theta + base + f) = *(const float4*)&xr[dn][c];
    }
}

// ---------------- Kernel A: coef = softmax_k(theta[n] . theta[idx[n,k]]) ----------------
// XCD-bijective swizzle: 1024 blocks = 8 XCDs x 128 -> each XCD works one
// contiguous half-batch => theta working set 2 MB per XCD L2.
__global__ __launch_bounds__(256) void kA(const int* __restrict__ gi,
                                          const float* __restrict__ theta,
                                          float* __restrict__ coefG) {
    __shared__ float tc[16][132];
    __shared__ float logits[16][33];
    int t = threadIdx.x;
    int bid = (blockIdx.x & 7) * 128 + (blockIdx.x >> 3);
    long trow0 = (long)bid * 16;
    int b = bid >> 8;
    int k = t >> 3, l8 = t & 7;
#pragma unroll
    for (int r = 0; r < 2; ++r) {
        int f = (t + 256*r) * 4;
        int dn = f >> 7, c = f & 127;
        *(float4*)&tc[dn][c] = *(const float4*)(theta + trow0*128 + f);
    }
    int idxs[16];
#pragma unroll
    for (int dn = 0; dn < 16; ++dn)
        idxs[dn] = gi[(trow0 + dn) * KK + k];
    __syncthreads();
    const float* tbat = theta + (long)b * NN * CC;
#pragma unroll 2
    for (int dn = 0; dn < 16; ++dn) {
        const float* row = tbat + (long)idxs[dn] * CC;
        float p = 0.f;
#pragma unroll
        for (int j = 0; j < 4; ++j) {
            int c = j*32 + l8*4;
            float4 g = *(const float4*)(row + c);
            float4 tcv = *(const float4*)&tc[dn][c];
            p += dot4(g, tcv);
        }
        p += __shfl_xor(p, 1);
        p += __shfl_xor(p, 2);
        p += __shfl_xor(p, 4);
        if (l8 == 0) logits[dn][k] = p;
    }
    __syncthreads();
    if (t < 128) {
        int row = t >> 3;
        float l[4];
#pragma unroll
        for (int j = 0; j < 4; ++j) l[j] = logits[row][l8 + 8*j];
        float m = fmaxf(fmaxf(l[0], l[1]), fmaxf(l[2], l[3]));
        m = fmaxf(m, __shfl_xor(m, 1));
        m = fmaxf(m, __shfl_xor(m, 2));
        m = fmaxf(m, __shfl_xor(m, 4));
        float e[4]; float s = 0.f;
#pragma unroll
        for (int j = 0; j < 4; ++j) { e[j] = __expf(l[j] - m); s += e[j]; }
        s += __shfl_xor(s, 1);
        s += __shfl_xor(s, 2);
        s += __shfl_xor(s, 4);
        float inv = 1.0f / s;
#pragma unroll
        for (int j = 0; j < 4; ++j)
            coefG[(trow0 + row) * KK + l8 + 8*j] = e[j] * inv;
    }
}

// ---------------- Kernel B: agg[n][c] = sum_k coef[n][k]*feature[b][c][n][k] ----------------
// 3-slot DMA ring, 2 chunks in flight, counted vmcnt (never 0 in loop).
__global__ __launch_bounds__(256) void kB(const float* __restrict__ coefG,
                                          const float* __restrict__ feat,
                                          float* __restrict__ aggG) {
    __shared__ float stage[3][4][32][32];   // [slot][c_local][n][k] 3x16KB
    __shared__ float aggL[32][36];
    int t = threadIdx.x;
    int cc4 = blockIdx.x & 3;
    int tile = blockIdx.x >> 2;          // b*128 + nt
    int b = tile >> 7;
    int n0 = (tile & 127) * 32;
    int dn = t >> 3, l8 = t & 7;
    int w = t >> 6, lane = t & 63;

    float4 cf = *(const float4*)(coefG + ((size_t)tile * 32 + dn) * KK + l8 * 4);
    // force cf into registers BEFORE any DMA issues, so the compiler's
    // waitcnt for cf doesn't drain the DMA pipeline inside the loop
    asm volatile("" :: "v"(cf.x), "v"(cf.y), "v"(cf.z), "v"(cf.w));

    const size_t S = (size_t)NN * KK;
    // per-lane global base: lane L covers bytes [L*16, L*16+16) of each 1KB row-group
    const float* fbase = feat + ((size_t)b * CC + cc4 * 32) * S + (size_t)n0 * KK + lane * 4;

    // prologue: stage chunks 0,1,2 into slots 0,1,2
#pragma unroll
    for (int ch = 0; ch < 3; ++ch) {
        const float* fc = fbase + (size_t)(ch * 4 + w) * S;
        float* ld = &stage[ch][w][0][0];
#pragma unroll
        for (int i = 0; i < 4; ++i)
            async_copy16(fc + i * 256, ld + i * 256);
    }

    int slot = 0;
#pragma unroll
    for (int ch = 0; ch < 8; ++ch) {
        // wait until this wave's chunk-ch loads (oldest 4) are done
        int rem = 7 - ch;
        if (rem >= 2)      asm volatile("s_waitcnt vmcnt(8)" ::: "memory");
        else if (rem == 1) asm volatile("s_waitcnt vmcnt(4)" ::: "memory");
        else               asm volatile("s_waitcnt vmcnt(0)" ::: "memory");
        SYNCB();   // all waves' chunk-ch staging complete
#pragma unroll
        for (int cl = 0; cl < 4; ++cl) {
            float4 f = *(const float4*)&stage[slot][cl][dn][l8 * 4];
            float v = dot4(f, cf);
            v += __shfl_xor(v, 1);
            v += __shfl_xor(v, 2);
            v += __shfl_xor(v, 4);
            if (l8 == 0) aggL[dn][ch * 4 + cl] = v;
        }
        SYNCB();   // all waves done reading this slot before restage
        if (ch + 3 < 8) {
            const float* fc = fbase + (size_t)((ch + 3) * 4 + w) * S;
            float* ld = &stage[slot][w][0][0];
#pragma unroll
            for (int i = 0; i < 4; ++i)
                async_copy16(fc + i * 256, ld + i * 256);
        }
        slot = (slot == 2) ? 0 : slot + 1;
    }
    __syncthreads();
    int row = t >> 3, col4 = l8 * 4;
    *(float4*)(aggG + ((size_t)b * NN + n0 + row) * CC + cc4 * 32 + col4) =
        *(const float4*)&aggL[row][col4];
}

// ---------------- Kernel C: y = agg @ M^T + b2; BN partials ----------------
__global__ __launch_bounds__(256) void kC(const float* __restrict__ aggG,
                                          const float* __restrict__ Mmat,
                                          const float* __restrict__ b2v,
                                          float* __restrict__ y,
                                          float* __restrict__ partial) {
    __shared__ float agg[32][132];
    __shared__ float mc[128][36];
    __shared__ float pw[4][128];
    __shared__ float qw[4][128];
    int t = threadIdx.x;
    int b = blockIdx.x >> 7;
    int n0 = (blockIdx.x & 127) * 32;
    long base = (long)blockIdx.x * (32 * 128);
#pragma unroll
    for (int r = 0; r < 4; ++r) {
        int f = (t + 256*r) * 4;
        int dn = f >> 7, c = f & 127;
        *(float4*)&agg[dn][c] = *(const float4*)(aggG + base + f);
    }
    float acc[4][4] = {};
    int e0 = t & 31, dn0 = (t >> 5) * 4;
    for (int cb = 0; cb < 4; ++cb) {
        __syncthreads();
#pragma unroll
        for (int r = 0; r < 4; ++r) {
            int f = (t + 256*r) * 4;
            int e = f >> 5, cc = f & 31;
            *(float4*)&mc[e][cc] = *(const float4*)(Mmat + e*128 + cb*32 + cc);
        }
        __syncthreads();
#pragma unroll
        for (int q = 0; q < 8; ++q) {
            float4 a4[4], m4[4];
#pragma unroll
            for (int j = 0; j < 4; ++j) a4[j] = *(const float4*)&agg[dn0+j][cb*32 + q*4];
#pragma unroll
            for (int i = 0; i < 4; ++i) m4[i] = *(const float4*)&mc[e0 + 32*i][q*4];
#pragma unroll
            for (int i = 0; i < 4; ++i)
#pragma unroll
                for (int j = 0; j < 4; ++j)
                    acc[i][j] += dot4(a4[j], m4[i]);
        }
        __syncthreads();
    }
    int w = t >> 6;
#pragma unroll
    for (int i = 0; i < 4; ++i) {
        int e = e0 + 32*i;
        float bb = b2v[e];
        float4 yv;
        yv.x = acc[i][0] + bb;
        yv.y = acc[i][1] + bb;
        yv.z = acc[i][2] + bb;
        yv.w = acc[i][3] + bb;
        *(float4*)(y + ((long)(b*CC + e)) * NN + n0 + dn0) = yv;
        float s = yv.x + yv.y + yv.z + yv.w;
        float qq = yv.x*yv.x + yv.y*yv.y + yv.z*yv.z + yv.w*yv.w;
        s  += __shfl_xor(s, 32);
        qq += __shfl_xor(qq, 32);
        if (!(t & 32)) { pw[w][e] = s; qw[w][e] = qq; }
    }
    __syncthreads();
    if (t < 128) {
        partial[(long)blockIdx.x * 256 + t]       = pw[0][t] + pw[1][t] + pw[2][t] + pw[3][t];
        partial[(long)blockIdx.x * 256 + 128 + t] = qw[0][t] + qw[1][t] + qw[2][t] + qw[3][t];
    }
}

// ---------------- Kernel R1: 512 partial rows -> 64 ----------------
__global__ __launch_bounds__(256) void kR1(const float* __restrict__ partial,
                                           float* __restrict__ partial2) {
    int t = threadIdx.x;
    long b0 = (long)blockIdx.x * 8;
    float acc = 0.f;
#pragma unroll
    for (int j = 0; j < 8; ++j)
        acc += partial[(b0 + j) * 256 + t];
    partial2[(long)blockIdx.x * 256 + t] = acc;
}

// ---------------- Kernel R2: 64 rows -> stats ----------------
__global__ __launch_bounds__(256) void kR2(const float* __restrict__ partial2,
                                           const float* __restrict__ gamma,
                                           const float* __restrict__ beta,
                                           float* __restrict__ stats) {
    __shared__ float buf[256];
    int t = threadIdx.x;
    float acc = 0.f;
#pragma unroll
    for (int j = 0; j < 64; ++j)
        acc += partial2[j * 256 + t];
    buf[t] = acc;
    __syncthreads();
    if (t < 128) {
        float S = buf[t], Q = buf[t + 128];
        const float invN = 1.0f / (BB * NN);
        float mean = S * invN;
        float var  = Q * invN - mean * mean;
        float sc = rsqrtf(var + 1e-5f) * gamma[t];
        stats[t]       = sc;
        stats[128 + t] = beta[t] - mean * sc;
    }
}

// ---------------- Kernel Z: in-place normalize ----------------
__global__ void kZ(float* __restrict__ y, const float* __restrict__ stats) {
    int idx = blockIdx.x * 256 + threadIdx.x;   // float4 index
#pragma unroll
    for (int r = 0; r < 2; ++r) {
        int i = idx + r * 262144;
        int e = (i >> 10) & 127;
        float sc = stats[e], sh = stats[128 + e];
        float4 v = ((float4*)y)[i];
        v.x = v.x * sc + sh;
        v.y = v.y * sc + sh;
        v.z = v.z * sc + sh;
        v.w = v.w * sc + sh;
        ((float4*)y)[i] = v;
    }
}

extern "C" void kernel_launch(void* const* d_in, const int* in_sizes, int n_in,
                              void* d_out, int out_size, void* d_ws, size_t ws_size,
                              hipStream_t stream) {
    const int*   gi    = (const int*)d_in[0];
    const float* x     = (const float*)d_in[1];
    const float* feat  = (const float*)d_in[2];
    const float* Wt    = (const float*)d_in[3];
    const float* bt    = (const float*)d_in[4];
    const float* Wg    = (const float*)d_in[5];
    const float* bg    = (const float*)d_in[6];
    const float* Ww    = (const float*)d_in[7];
    const float* bw    = (const float*)d_in[8];
    const float* gamma = (const float*)d_in[9];
    const float* beta  = (const float*)d_in[10];

    float* y  = (float*)d_out;
    float* ws = (float*)d_ws;
    float* theta    = ws + THETA_OFF;
    float* aggG     = ws + AGG_OFF;
    float* Mmat     = ws + M_OFF;
    float* b2       = ws + B2_OFF;
    float* coefG    = ws + COEF_OFF;
    float* partial  = ws + PART_OFF;
    float* partial2 = ws + PART2_OFF;
    float* stats    = ws + STAT_OFF;

    kWT<<<577, 256, 0, stream>>>(x, Wt, bt, Ww, Wg, bg, bw, theta, Mmat, b2);
    kA<<<1024, 256, 0, stream>>>(gi, theta, coefG);
    kB<<<2048, 256, 0, stream>>>(coefG, feat, aggG);
    kC<<<512, 256, 0, stream>>>(aggG, Mmat, b2, y, partial);
    kR1<<<64, 256, 0, stream>>>(partial, partial2);
    kR2<<<1, 256, 0, stream>>>(partial2, gamma, beta, stats);
    kZ<<<1024, 256, 0, stream>>>(y, stats);
}